// Round 15
// baseline (483.877 us; speedup 1.0000x reference)
//
#include <hip/hip_runtime.h>
#include <hip/hip_bf16.h>

typedef short bf16x8 __attribute__((ext_vector_type(8)));   // 8 bf16 in 4 VGPRs
typedef float f32x4  __attribute__((ext_vector_type(4)));

constexpr int B = 8, T = 10, F = 64, CO = 256;
constexpr long IMGPIX      = 48 * 48;                // 2304
constexpr long STATE_ELEMS = (long)B * IMGPIX * F;   // 1,179,648
constexpr float BN_INVN    = 1.0f / (float)(B * T * IMGPIX);

__device__ __forceinline__ float  b2f(ushort u) { return __uint_as_float(((unsigned)u) << 16); }
__device__ __forceinline__ ushort f2b(float f) {
    unsigned x = __float_as_uint(f);
    return (ushort)((x + 0x7fffu + ((x >> 16) & 1u)) >> 16);   // RNE
}
__device__ __forceinline__ float hsig(float x) { return fminf(fmaxf(0.2f * x + 0.5f, 0.f), 1.f); }
__device__ __forceinline__ float tanh_f(float v) {
    return 1.f - 2.f / (__expf(2.f * v) + 1.f);    // exact at +/-inf, ~1e-6 err
}

union V16 { uint4 u; bf16x8 b; };

// ---------------------------------------------------------------------------
// Full-K MFMA loop, segment-major weights, static A-addressing (R14-verified).
// One wave computes 48px x {all 4 gates} x 16 f-channels: acc[m][gate][r].
// ---------------------------------------------------------------------------
template<int CIN_A, int CPAD>
__device__ __forceinline__ void mfma_loop(
    const unsigned char* __restrict__ pA,    // smem + (lm*CPAD + lk8)*2
    const ushort* __restrict__ Wsw,
    int q, int l, f32x4 (&acc)[3][4])
{
    constexpr int KX  = 9 * CIN_A;
    constexpr int KSX = (KX + 31) / 32;
    constexpr int KS  = KSX + 18;
    const int lk8 = (l >> 4) * 8;

#pragma unroll
    for (int ks = 0; ks < KS; ++ks) {
        V16 bf[4];
#pragma unroll
        for (int nr = 0; nr < 4; ++nr) {
            const int ntile = nr * 4 + q;
            bf[nr].u = *(const uint4*)(Wsw + ((size_t)((ntile * KS + ks) * 64) + l) * 8);
        }
        V16 af[3];
        if (CIN_A == 64 || ks >= KSX) {
            // ---- static 64-channel segment: tap/ch compile-time under unroll ----
            const int base_ch = (CIN_A == 64 && ks < KSX) ? 0 : CIN_A;
            const int khs     = (CIN_A == 64 && ks < KSX) ? ks : ks - KSX;
            const int tap = khs >> 1;
            const int ky = tap / 3, kx = tap - 3 * (tap / 3);
            const int ch = base_ch + (khs & 1) * 32;
#pragma unroll
            for (int m = 0; m < 3; ++m) {
                const int IMM = ((ky * 50 + kx + m * 16) * CPAD + ch) * 2;
                af[m].u = *(const uint4*)(pA + IMM);
            }
        } else {
            // ---- generic x-segment (L1, CIN_A=16; 5 iterations) ----
            const int k = ks * 32 + lk8;
            const bool valid = (k < KX);
            const int tap = valid ? (2 * ks + (lk8 >> 4)) : 0;   // k/16
            const int ky = tap / 3, kx = tap - 3 * (tap / 3);
            const int dci = (lk8 & 16) * 2;                      // ci0-lk8 offset
#pragma unroll
            for (int m = 0; m < 3; ++m) {
                const int base = ((ky * 50 + kx + m * 16) * CPAD) * 2;
                uint4 v = *(const uint4*)(pA + (valid ? base - dci : 0));
                if (!valid) v = make_uint4(0, 0, 0, 0);
                af[m].u = v;
            }
        }
#pragma unroll
        for (int m = 0; m < 3; ++m)
#pragma unroll
            for (int nr = 0; nr < 4; ++nr)
                acc[m][nr] = __builtin_amdgcn_mfma_f32_16x16x32_bf16(
                    af[m].b, bf[nr].b, acc[m][nr], 0, 0, 0);
    }
}

// ---------------------------------------------------------------------------
// Fused ConvLSTM step, barrier-light version.  Grid = 768 (img, row, half),
// block = 128 threads = 2 waves.  Wave wid: q = 2*half + wid owns f-channels
// [q*16,(q+1)*16) x all 4 gates x 48 pixels, full K -- so after ONE staging
// barrier the wave runs K-loop + lane-local LSTM update with no further
// synchronization (acc[m][gate][r] holds i,f,c,o for the same (pixel,ch)).
// ---------------------------------------------------------------------------
template<int CIN_A, int CPAD, bool FIRST, bool STATS, bool BNIN, bool OUT>
__global__ __launch_bounds__(128) void convlstm_step(
    const ushort* __restrict__ inA, long strideA,   // per-img stride (elements)
    const ushort* __restrict__ inB,                 // h_prev (B,2304,64) bf16
    const ushort* __restrict__ Wsw,                 // swizzled [ntile][KS][64][8]
    const float*  __restrict__ bias,                // (256)
    float*  __restrict__ cState,                    // (B,2304,64) f32 in place
    ushort* __restrict__ hOut,                      // (B,2304,64) bf16
    ushort* __restrict__ seqOut,                    // STATS only
    float*  __restrict__ stats,                     // [128]
    const float* __restrict__ gamma,
    const float* __restrict__ beta,
    float*  __restrict__ outF)                      // OUT only
{
    constexpr int CIN_TOT = CIN_A + 64;
    constexpr int PATCHB = 3 * 50 * CPAD * 2;
    __shared__ __align__(16) unsigned char smem[PATCHB];
    __shared__ float bnsc[64], bnsh[64];

    const int bid  = blockIdx.x;
    const int img  = bid / 96;
    const int rem  = bid % 96;
    const int y    = rem >> 1;
    const int half = rem & 1;
    const int tid = threadIdx.x, wid = tid >> 6, l = tid & 63;
    const int lm = l & 15, lk8 = (l >> 4) * 8;

    if constexpr (BNIN) {
        if (tid < 64) {
            const float mean = stats[tid] * BN_INVN;
            const float var  = stats[64 + tid] * BN_INVN - mean * mean;
            const float sc   = gamma[tid] * rsqrtf(var + 1e-3f);
            bnsc[tid] = sc;
            bnsh[tid] = beta[tid] - mean * sc;
        }
        __syncthreads();
    }

    // ---- stage 3 x 50 x CIN_TOT patch (zero-padded), padded channel stride ----
    const ushort* aBase = inA + (size_t)img * strideA;
    const ushort* bBase = inB + (size_t)img * IMGPIX * 64;
    constexpr int CA8 = CIN_A / 8;
    for (int e = tid; e < 3 * 48 * CA8; e += 128) {           // x/seq channels
        const int r = e / (48 * CA8), qq = e % (48 * CA8);
        const int col = qq / CA8, ci0 = (qq % CA8) * 8;
        const int gy = y + r - 1;
        uint4 v = make_uint4(0, 0, 0, 0);
        if (gy >= 0 && gy < 48) {
            v = *(const uint4*)(aBase + ((size_t)gy * 48 + col) * CIN_A + ci0);
            if constexpr (BNIN) {      // BN only on real pixels; padding stays 0
                ushort* u = (ushort*)&v;
#pragma unroll
                for (int j = 0; j < 8; ++j)
                    u[j] = f2b(b2f(u[j]) * bnsc[ci0 + j] + bnsh[ci0 + j]);
            }
        }
        *(uint4*)(smem + ((r * 50 + col + 1) * CPAD + ci0) * 2) = v;
    }
    for (int e = tid; e < 3 * 48 * 8; e += 128) {             // h channels
        const int r = e / (48 * 8), qq = e % (48 * 8);
        const int col = qq / 8, ci0 = (qq % 8) * 8;
        uint4 v = make_uint4(0, 0, 0, 0);
        if constexpr (!FIRST) {
            const int gy = y + r - 1;
            if (gy >= 0 && gy < 48)
                v = *(const uint4*)(bBase + ((size_t)gy * 48 + col) * 64 + ci0);
        }
        *(uint4*)(smem + ((r * 50 + col + 1) * CPAD + CIN_A + ci0) * 2) = v;
    }
    constexpr int CT8 = CIN_TOT / 8;
    for (int e = tid; e < 3 * 2 * CT8; e += 128) {            // pad cols 0 and 49
        const int r = e / (2 * CT8), qq = e % (2 * CT8);
        const int dc = (qq / CT8) ? 49 : 0, ci0 = (qq % CT8) * 8;
        *(uint4*)(smem + ((r * 50 + dc) * CPAD + ci0) * 2) = make_uint4(0, 0, 0, 0);
    }
    __syncthreads();                      // the ONLY post-stage barrier

    const int q = 2 * half + wid;
    const unsigned char* pA = smem + (lm * CPAD + lk8) * 2;

    f32x4 acc[3][4] = {};
    mfma_loop<CIN_A, CPAD>(pA, Wsw, q, l, acc);

    // ---- lane-local LSTM gate/state update: acc[m][gate][r] ----
    const float bv_i = bias[      q * 16 + lm];
    const float bv_f = bias[ 64 + q * 16 + lm];
    const float bv_c = bias[128 + q * 16 + lm];
    const float bv_o = bias[192 + q * 16 + lm];

    float s1 = 0.f, s2 = 0.f;
    const size_t rowBase = (size_t)img * IMGPIX + (size_t)y * 48;
#pragma unroll
    for (int m = 0; m < 3; ++m)
#pragma unroll
        for (int r = 0; r < 4; ++r) {
            const int p = m * 16 + (l >> 4) * 4 + r;
            const float gi = acc[m][0][r] + bv_i;
            const float gf = acc[m][1][r] + bv_f;
            const float gc = acc[m][2][r] + bv_c;
            const float go = acc[m][3][r] + bv_o;
            const size_t off = (rowBase + p) * 64 + q * 16 + lm;
            const float cold = FIRST ? 0.f : cState[off];
            const float cn = hsig(gf) * cold + hsig(gi) * tanh_f(gc);
            const float hn = hsig(go) * tanh_f(cn);
            cState[off] = cn;
            hOut[off]   = f2b(hn);
            if constexpr (STATS) { seqOut[off] = f2b(hn); s1 += hn; s2 += hn * hn; }
            if constexpr (OUT)   { outF[off] = hn; outF[STATE_ELEMS + off] = cn; }
        }

    if constexpr (STATS) {
        // lanes sharing lm (l ^ 16, l ^ 32) hold the same channel
        s1 += __shfl_xor(s1, 16);  s2 += __shfl_xor(s2, 16);
        s1 += __shfl_xor(s1, 32);  s2 += __shfl_xor(s2, 32);
        if (l < 16) {
            atomicAdd(&stats[     q * 16 + lm], s1);
            atomicAdd(&stats[64 + q * 16 + lm], s2);
        }
    }
}

// ---------------------------------------------------------------------------
// Prep: cast x to bf16, build segment-major swizzled concat weights, zero stats.
// k-order: [x-taps (9*CIN_A, zero-padded to KSX*32) ; h-taps (576)].
// ---------------------------------------------------------------------------
__device__ __forceinline__ ushort swz_elem_seg(
    const float* __restrict__ Wx, const float* __restrict__ Wh,
    int CIN_A, int idx)
{
    const int KX = 9 * CIN_A, KSX = (KX + 31) / 32, KS = KSX + 18;
    const int j = idx & 7, lw = (idx >> 3) & 63, rest = idx >> 9;
    const int ks = rest % KS, ntile = rest / KS;
    const int n = ntile * 16 + (lw & 15);
    const int k = ks * 32 + ((lw >> 4) & 3) * 8 + j;
    float v = 0.f;
    if (ks < KSX) {
        if (k < KX) {
            const int tap = k / CIN_A, ci = k % CIN_A;
            v = Wx[((size_t)tap * CIN_A + ci) * CO + n];
        }
    } else {
        const int kh = k - KSX * 32;                 // 0..575
        const int tap = kh >> 6, ci = kh & 63;
        v = Wh[((size_t)tap * 64 + ci) * CO + n];
    }
    return f2b(v);
}

__global__ __launch_bounds__(256) void prep_kernel(
    const float* __restrict__ x,
    const float* __restrict__ Wx1, const float* __restrict__ Wh1,
    const float* __restrict__ Wx2, const float* __restrict__ Wh2,
    ushort* __restrict__ xb, ushort* __restrict__ wc1, ushort* __restrict__ wc2,
    float* __restrict__ stats)
{
    constexpr int N0 = 368640;          // x: 2,949,120 elems / 8
    constexpr int N1 = 16 * 23 * 512;   // 188,416 (KS=5+18)
    constexpr int N2 = 16 * 36 * 512;   // 294,912 (KS=18+18)
    const int gid = blockIdx.x * 256 + threadIdx.x;
    if (gid < N0) {
        const float4 a = ((const float4*)x)[(size_t)gid * 2];
        const float4 b = ((const float4*)x)[(size_t)gid * 2 + 1];
        ushort o[8] = { f2b(a.x), f2b(a.y), f2b(a.z), f2b(a.w),
                        f2b(b.x), f2b(b.y), f2b(b.z), f2b(b.w) };
        *(uint4*)(xb + (size_t)gid * 8) = *(const uint4*)o;
    } else if (gid < N0 + N1) {
        wc1[gid - N0] = swz_elem_seg(Wx1, Wh1, 16, gid - N0);
    } else if (gid < N0 + N1 + N2) {
        wc2[gid - N0 - N1] = swz_elem_seg(Wx2, Wh2, 64, gid - N0 - N1);
    } else if (gid < N0 + N1 + N2 + 128) {
        stats[gid - N0 - N1 - N2] = 0.f;
    }
}

// ---------------------------------------------------------------------------
extern "C" void kernel_launch(void* const* d_in, const int* in_sizes, int n_in,
                              void* d_out, int out_size, void* d_ws, size_t ws_size,
                              hipStream_t stream)
{
    const float* x      = (const float*)d_in[0];
    const float* Wx1    = (const float*)d_in[1];
    const float* Wh1    = (const float*)d_in[2];
    const float* b1     = (const float*)d_in[3];
    const float* gamma1 = (const float*)d_in[4];
    const float* beta1  = (const float*)d_in[5];
    const float* Wx2    = (const float*)d_in[6];
    const float* Wh2    = (const float*)d_in[7];
    const float* b2     = (const float*)d_in[8];

    // workspace layout (bytes) -- ~49 MB of the 256 MB ws
    unsigned char* w = (unsigned char*)d_ws;
    ushort* seq1 = (ushort*)w;  w += 23592960;   // (T,B,2304,64) bf16
    ushort* xb   = (ushort*)w;  w += 5898240;    // (B,T,2304,16) bf16
    ushort* wc1  = (ushort*)w;  w += 376832;     // 16*23*512 u16
    ushort* wc2  = (ushort*)w;  w += 589824;     // 16*36*512 u16
    ushort* hb1a = (ushort*)w;  w += 2359296;
    ushort* hb1b = (ushort*)w;  w += 2359296;
    ushort* hb2a = (ushort*)w;  w += 2359296;
    ushort* hb2b = (ushort*)w;  w += 2359296;
    float*  c1   = (float*)w;   w += 4718592;
    float*  c2   = (float*)w;   w += 4718592;
    float*  stats = (float*)w;  w += 512;

    prep_kernel<<<3329, 256, 0, stream>>>(x, Wx1, Wh1, Wx2, Wh2, xb, wc1, wc2, stats);

    const long xStride = (long)T * IMGPIX * 16;
    ushort* hp1[2] = { hb1a, hb1b };

    // ----- layer 1 (STATS: accumulate BN sums; t=9 also writes d_out h1,c1) -----
    convlstm_step<16, 88, true, true, false, false><<<768, 128, 0, stream>>>(
        xb, xStride, hp1[0], wc1, b1, c1, hp1[1],
        seq1, stats, nullptr, nullptr, nullptr);
    for (int t = 1; t < 9; ++t)
        convlstm_step<16, 88, false, true, false, false><<<768, 128, 0, stream>>>(
            xb + (size_t)t * IMGPIX * 16, xStride, hp1[t & 1], wc1, b1, c1, hp1[(t + 1) & 1],
            seq1 + (size_t)t * STATE_ELEMS, stats, nullptr, nullptr, nullptr);
    convlstm_step<16, 88, false, true, false, true><<<768, 128, 0, stream>>>(
        xb + (size_t)9 * IMGPIX * 16, xStride, hp1[1], wc1, b1, c1, hp1[0],
        seq1 + (size_t)9 * STATE_ELEMS, stats, nullptr, nullptr, (float*)d_out);

    // ----- layer 2 (BNIN: normalize seq1 on the fly; t=9 writes d_out h2,c2) -----
    ushort* hp2[2] = { hb2a, hb2b };
    convlstm_step<64, 136, true, false, true, false><<<768, 128, 0, stream>>>(
        seq1, IMGPIX * 64, hp2[0], wc2, b2, c2, hp2[1],
        nullptr, stats, gamma1, beta1, nullptr);
    for (int t = 1; t < 9; ++t)
        convlstm_step<64, 136, false, false, true, false><<<768, 128, 0, stream>>>(
            seq1 + (size_t)t * STATE_ELEMS, IMGPIX * 64, hp2[t & 1], wc2, b2, c2, hp2[(t + 1) & 1],
            nullptr, stats, gamma1, beta1, nullptr);
    convlstm_step<64, 136, false, false, true, true><<<768, 128, 0, stream>>>(
        seq1 + (size_t)9 * STATE_ELEMS, IMGPIX * 64, hp2[1], wc2, b2, c2, hp2[0],
        nullptr, stats, gamma1, beta1, (float*)d_out + 2 * STATE_ELEMS);
}